// Round 5
// baseline (119.403 us; speedup 1.0000x reference)
//
#include <hip/hip_runtime.h>

// 256 independent LSAP problems (Jonker-Volgenant / scipy-trajectory-exact),
// one wave per problem, lane j owns column j and row j's dual state.
// All solver state in registers; cross-lane via DPP/readlane. LDS holds only
// the cost matrix. All arithmetic double, numpy-identical expression order.
// Fast path: argmin butterfly on u32-compressed keys (exact order embedding
// for on-grid float32 inputs); fallback: f64 butterfly (verified round-3).

union DU { double d; int i2[2]; };

__device__ inline double readlane_f64(double x, int l) {
    DU a; a.d = x;
    DU o;
    o.i2[0] = __builtin_amdgcn_readlane(a.i2[0], l);
    o.i2[1] = __builtin_amdgcn_readlane(a.i2[1], l);
    return o.d;
}

template <int CTRL>
__device__ inline double dpp_min_f64(double x) {
    DU a; a.d = x;
    DU b;
    b.i2[0] = __builtin_amdgcn_update_dpp(0, a.i2[0], CTRL, 0xF, 0xF, true);
    b.i2[1] = __builtin_amdgcn_update_dpp(0, a.i2[1], CTRL, 0xF, 0xF, true);
    return fmin(x, b.d);
}

template <int CTRL>
__device__ inline unsigned dpp_u32_full(unsigned x) {
    return (unsigned)__builtin_amdgcn_update_dpp(0, (int)x, CTRL, 0xF, 0xF, true);
}

template <int CTRL, int RMASK>
__device__ inline unsigned dpp_u32_keep(unsigned x) {
    // masked-off rows keep old (=x); enabled rows receive broadcast value
    return (unsigned)__builtin_amdgcn_update_dpp((int)x, (int)x, CTRL, RMASK, 0xF, false);
}

__device__ inline unsigned umin_(unsigned a, unsigned b) { return a < b ? a : b; }

// Wave argmin over u32 keys, lowest-lane tie-break. Returns jsel.
__device__ inline int wave_argmin_u32(unsigned key) {
    unsigned k = key;
    k = umin_(k, dpp_u32_full<0xB1>(k));    // quad_perm {1,0,3,2}  (xor 1)
    k = umin_(k, dpp_u32_full<0x4E>(k));    // quad_perm {2,3,0,1}  (xor 2)
    k = umin_(k, dpp_u32_full<0x141>(k));   // ROW_HALF_MIRROR      (xor 4)
    k = umin_(k, dpp_u32_full<0x140>(k));   // ROW_MIRROR           (xor 8)
    k = umin_(k, dpp_u32_keep<0x142, 0xA>(k)); // ROW_BCAST15 -> rows 1,3
    k = umin_(k, dpp_u32_keep<0x143, 0xC>(k)); // ROW_BCAST31 -> rows 2,3
    const unsigned gmin = (unsigned)__builtin_amdgcn_readlane((int)k, 63);
    const unsigned long long eq = __ballot(key == gmin);
    return __ffsll(eq) - 1;
}

// One full solve. FAST: u32-compressed argmin (exact for on-grid inputs).
template <bool FAST>
__device__ void run_lsap(const float* __restrict__ costL, int lane, int c,
                         double& u_d, double& v_d,
                         int& path_r, int& row4col_r, int& col4row_r)
{
    const double INF = __builtin_inf();

    for (int cur_row = 0; cur_row < c; ++cur_row) {
        double minv_d    = INF;    // shortest path cost to column `lane`
        bool   remaining = true;
        unsigned long long SR = 0ULL;
        int    i       = cur_row;  // wave-uniform
        double min_val = 0.0;
        int    sink    = -1;

        while (sink < 0) {
            SR |= 1ULL << i;
            const double u_i = readlane_f64(u_d, i);        // broadcast
            const float  cf  = costL[i * 64 + lane];        // the one DS op
            // numpy order: ((min_val + cost) - u) - v  (adds only, no FMA)
            double r = min_val + (double)cf;
            r = r - u_i;
            r = r - v_d;
            const bool upd = remaining && (r < minv_d);
            minv_d = upd ? r : minv_d;
            path_r = upd ? i : path_r;

            int jsel;
            if (FAST) {
                // exact order-embedding: m = minv * 2^23 (exact integer on grid)
                const double scaled = minv_d * 8388608.0;
                const bool ok = remaining && (scaled >= 0.0) && (scaled < 4294967040.0);
                const unsigned key = ok ? (unsigned)scaled : 0xFFFFFFFFu;
                jsel   = wave_argmin_u32(key);
                min_val = readlane_f64(minv_d, jsel);       // exact f64 value
            } else {
                const double key = remaining ? minv_d : INF;
                double k = dpp_min_f64<0xB1>(key);
                k = dpp_min_f64<0x4E>(k);
                k = dpp_min_f64<0x141>(k);
                k = dpp_min_f64<0x140>(k);
                const double m0 = readlane_f64(k, 0);
                const double m1 = readlane_f64(k, 16);
                const double m2 = readlane_f64(k, 32);
                const double m3 = readlane_f64(k, 48);
                const double kmin = fmin(fmin(m0, m1), fmin(m2, m3));
                const unsigned long long eq = __ballot(key == kmin);
                jsel    = __ffsll(eq) - 1;
                min_val = kmin;
            }

            remaining = remaining && (lane != jsel);
            const int rj = __builtin_amdgcn_readlane(row4col_r, jsel);
            if (rj < 0) sink = jsel; else i = rj;
        }

        // ---- dual updates (reference formulas, pre-augment col4row) ----
        {
            const bool scanned_row = (SR >> lane) & 1ULL;
            const int  gidx = col4row_r & 63;               // clamp -1 -> unused
            const double mv_g = __shfl(minv_d, gidx, 64);   // minv[col4row[lane]]
            if (lane == cur_row)       u_d += min_val;
            else if (scanned_row)      u_d += min_val - mv_g;
            if (!remaining)            v_d -= min_val - minv_d;  // scanned cols
        }

        // ---- augment along alternating path (predicated lane writes) ----
        {
            int jj = sink;
            while (true) {
                const int ii = __builtin_amdgcn_readlane(path_r, jj);
                if (lane == jj) row4col_r = ii;
                const int tmp = __builtin_amdgcn_readlane(col4row_r, ii);
                if (lane == ii) col4row_r = jj;
                jj = tmp;
                if (ii == cur_row) break;
            }
        }
    }
}

__global__ __launch_bounds__(64)
void lsap_solve(const float* __restrict__ cost,
                const float* __restrict__ gt,
                float* __restrict__ out,
                double* __restrict__ partial)
{
    const int b    = blockIdx.x;
    const int lane = threadIdx.x;          // column index (and row index for u)

    __shared__ float costL[64 * 64];       // row-major [row][col]
    __shared__ int   ordL[64];

    // ---- stage cost matrix to LDS (coalesced float4) ----
    const float4* cb4 = (const float4*)(cost + (size_t)b * 4096);
    float4*       cl4 = (float4*)costL;
#pragma unroll
    for (int i = 0; i < 16; ++i)
        cl4[i * 64 + lane] = cb4[i * 64 + lane];

    // ---- valid-box count: first all-zero [2,3] box ----
    const float* gb = gt + (size_t)b * 384 + lane * 6;
    bool iszero = true;
#pragma unroll
    for (int k = 0; k < 6; ++k) iszero = iszero && (gb[k] == 0.0f);
    unsigned long long zmask = __ballot(iszero);
    const int c = zmask ? (__ffsll(zmask) - 1) : 64;

    // ---- lane-private solver state ----
    double u_d = 0.0;          // u[lane]       (lane as row)
    double v_d = 0.0;          // v[lane]       (lane as col)
    int path_r    = -1;        // path[lane]    (lane as col)
    int row4col_r = -1;        // row4col[lane] (lane as col)
    int col4row_r = -1;        // col4row[lane] (lane as row)

    __syncthreads();           // costL visible

    // ---- on-grid check: every entry an exact multiple of 2^-23 in [0,2) ----
    bool ongrid = true;
    for (int i = 0; i < 64; ++i) {
        const double hd = (double)costL[i * 64 + lane] * 8388608.0;
        ongrid = ongrid && (hd >= 0.0) && (hd < 16777216.0) && (hd == floor(hd));
    }
    const bool fast = (__ballot(ongrid) == ~0ULL);

    if (fast) run_lsap<true >(costL, lane, c, u_d, v_d, path_r, row4col_r, col4row_r);
    else      run_lsap<false>(costL, lane, c, u_d, v_d, path_r, row4col_r, col4row_r);

    // ---- ordering = concat(col4row[0:c], sorted unassigned columns) ----
    const bool assigned = (row4col_r >= 0);                 // lane as col
    const unsigned long long amask = __ballot(assigned);
    if (lane < c) ordL[lane] = col4row_r;                   // lane as row
    if (!assigned) {
        const unsigned long long below = (~amask) & ((1ULL << lane) - 1ULL);
        ordL[c + __popcll(below)] = lane;
    }
    __syncthreads();

    const int oc = ordL[lane];
    out[b * 64 + lane] = (float)oc;

    // ---- per-block loss partial: sum_r cost[r, ordering[r]] ----
    double p = (double)costL[lane * 64 + oc];
#pragma unroll
    for (int s = 1; s < 64; s <<= 1) p += __shfl_xor(p, s, 64);
    if (lane == 0) partial[b] = p;
}

__global__ __launch_bounds__(256)
void loss_reduce(const double* __restrict__ partial, float* __restrict__ out,
                 int B)
{
    const int t = threadIdx.x;
    __shared__ double sb[4];
    double p = 0.0;
    for (int idx = t; idx < B; idx += 256) p += partial[idx];
#pragma unroll
    for (int s = 1; s < 64; s <<= 1) p += __shfl_xor(p, s, 64);
    if ((t & 63) == 0) sb[t >> 6] = p;
    __syncthreads();
    if (t == 0)
        out[B * 64] = (float)((sb[0] + sb[1] + sb[2] + sb[3]) / (double)(B * 64));
}

extern "C" void kernel_launch(void* const* d_in, const int* in_sizes, int n_in,
                              void* d_out, int out_size, void* d_ws, size_t ws_size,
                              hipStream_t stream)
{
    const float* cost = (const float*)d_in[0];   // [B,64,64] f32
    const float* gt   = (const float*)d_in[1];   // [B,64,2,3] f32
    float* out        = (float*)d_out;           // [B*64] ordering + [1] loss
    double* partial   = (double*)d_ws;           // B doubles of scratch

    const int B = in_sizes[0] / 4096;            // 64*64 per problem

    lsap_solve<<<B, 64, 0, stream>>>(cost, gt, out, partial);
    loss_reduce<<<1, 256, 0, stream>>>(partial, out, B);
}